// Round 4
// baseline (902.313 us; speedup 1.0000x reference)
//
#include <hip/hip_runtime.h>

#define NCONE 8
#define NDIM 24          // NC*3
#define PGD_ITERS 100
#define BATCH 65536
#define BLOCKT 256       // 1 batch element per thread; 1024 waves = 1 wave/SIMD chip-wide
#define POW_ITERS 80

__device__ __forceinline__ float fast_sqrt(float x) { return __builtin_amdgcn_sqrtf(x); }
__device__ __forceinline__ float fast_rcp(float x)  { return __builtin_amdgcn_rcpf(x); }

// SOC projection of one cone (head t, tail (x0,x1)) — matches reference.
__device__ __forceinline__ void soc_proj(float& t, float& x0, float& x1) {
    float n      = fast_sqrt(fmaf(x0, x0, x1 * x1));
    float coef   = 0.5f * (t + n);
    float safe_n = (n > 0.0f) ? n : 1.0f;
    float sc     = coef * fast_rcp(safe_n);
    bool inside  = (n <= t);
    bool below   = (n <= -t);
    float tn = inside ? t    : (below ? 0.0f : coef);
    float s  = inside ? 1.0f : (below ? 0.0f : sc);
    t = tn; x0 *= s; x1 *= s;
}

// ---------------------------------------------------------------------------
// Fused kernel, v4.
//
// R1: LICM hoisted loop-invariant P -> 256 VGPR + 2.7 GB scratch spill.
// R2: asm memory clobber fixed spill; 349 us, LDS-issue-bound
//     (4 waves/CU x 144 uniform ds_read_b128/iter x ~13 cyc).
// R3: 2 elem/thread halved LDS pressure but dropped to 2 waves/CU ->
//     latency-bound, 396 us. LDS-broadcast of P is structurally >=300 us.
//
// v4: P is wave-uniform -> stream it through SGPRs via s_load (scalar pipe,
// separate from VALU and LDS). Main loop has ZERO LDS traffic; the wave is
// VALU-issue-bound: 576 v_fma x 2cyc + projection ~= 1400 cyc/iter -> ~60 us.
// Pointer laundering (volatile asm "+s" + readfirstlane, NO memory clobber)
// makes the P address opaque per iteration: LICM can't hoist 576 values
// (R1 failure), while loads stay uniform + unclobbered -> SMEM-selected.
// ---------------------------------------------------------------------------
__global__ __launch_bounds__(BLOCKT, 1) void pgd_fused(const float* __restrict__ P,
                                                       const float* __restrict__ q,
                                                       float* __restrict__ out) {
    __shared__ __align__(16) float sP[NDIM * NDIM];   // for power iteration only
    __shared__ float sQ[BLOCKT * (NDIM + 1)];         // coalescing buffer, stride 25

    const int tid  = threadIdx.x;
    const int base = blockIdx.x * (BLOCKT * NDIM);

    for (int i = tid; i < NDIM * NDIM; i += BLOCKT)
        sP[i] = P[i];
    for (int idx = tid; idx < BLOCKT * NDIM; idx += BLOCKT) {
        int r = idx / NDIM;
        int c = idx - r * NDIM;
        sQ[r * (NDIM + 1) + c] = q[base + idx];
    }
    __syncthreads();

    // --- step = 1/lambda_max(P): per-wave power iteration + Rayleigh ---
    // (zero inter-block state — R2's graph-replay divergence lesson)
    const int lane = tid & 63;
    float step;
    {
        float p[NDIM];
#pragma unroll
        for (int j = 0; j < NDIM; ++j)
            p[j] = (lane < NDIM) ? sP[lane * NDIM + j] : 0.0f;
        float v = (lane < NDIM) ? (1.0f + 0.01f * (float)lane) : 0.0f;

        for (int it = 0; it < POW_ITERS; ++it) {
            float w = 0.0f;
#pragma unroll
            for (int j = 0; j < NDIM; ++j)
                w = fmaf(p[j], __shfl(v, j, 64), w);
            float n2 = w * w;
#pragma unroll
            for (int off = 32; off >= 1; off >>= 1)
                n2 += __shfl_xor(n2, off, 64);
            v = w * rsqrtf(n2);
        }
        float w = 0.0f;
#pragma unroll
        for (int j = 0; j < NDIM; ++j)
            w = fmaf(p[j], __shfl(v, j, 64), w);
        float num = v * w;
        float den = v * v;
#pragma unroll
        for (int off = 32; off >= 1; off >>= 1) {
            num += __shfl_xor(num, off, 64);
            den += __shfl_xor(den, off, 64);
        }
        step = den / num;   // identical on every lane/wave/block
    }

    // --- per-thread state in VGPRs ---
    float lq[NDIM], l[NDIM];
#pragma unroll
    for (int j = 0; j < NDIM; ++j) {
        lq[j] = sQ[tid * (NDIM + 1) + j];
        l[j]  = 0.0f;
    }

    const float* Pu = P;   // laundered each iteration

#pragma clang loop unroll(disable)
    for (int it = 0; it < PGD_ITERS; ++it) {
        // Launder the P pointer: opaque (defeats LICM hoisting — R1) but
        // uniform (readfirstlane) and NOT a memory clobber (keeps the loads
        // SMEM-eligible: s_load into SGPRs on the scalar pipe).
        asm volatile("" : "+s"(Pu));
        {
            unsigned long long a = (unsigned long long)Pu;
            unsigned lo = __builtin_amdgcn_readfirstlane((unsigned)a);
            unsigned hi = __builtin_amdgcn_readfirstlane((unsigned)(a >> 32));
            Pu = (const float*)((((unsigned long long)hi) << 32) | lo);
        }

        float g[NDIM];
#pragma unroll
        for (int j = 0; j < NDIM; ++j)
            g[j] = lq[j];

        // g += P^T l  (P symmetric): row i of P scaled by l[i], accumulated.
        // P reads are uniform scalar loads; v_fma takes the SGPR directly.
#pragma unroll
        for (int i = 0; i < NDIM; ++i) {
            float li = l[i];
#pragma unroll
            for (int j = 0; j < NDIM; ++j)
                g[j] = fmaf(li, Pu[i * NDIM + j], g[j]);
        }

        // y = l - step*g
#pragma unroll
        for (int j = 0; j < NDIM; ++j)
            g[j] = fmaf(-step, g[j], l[j]);

        // project onto product of 8 SOCs
#pragma unroll
        for (int c = 0; c < NCONE; ++c)
            soc_proj(g[c], g[NCONE + 2 * c], g[NCONE + 2 * c + 1]);

#pragma unroll
        for (int j = 0; j < NDIM; ++j)
            l[j] = g[j];
    }

    // --- coalesced store through padded LDS ---
    __syncthreads();
#pragma unroll
    for (int j = 0; j < NDIM; ++j)
        sQ[tid * (NDIM + 1) + j] = l[j];
    __syncthreads();
    for (int idx = tid; idx < BLOCKT * NDIM; idx += BLOCKT) {
        int r = idx / NDIM;
        int c = idx - r * NDIM;
        out[base + idx] = sQ[r * (NDIM + 1) + c];
    }
}

extern "C" void kernel_launch(void* const* d_in, const int* in_sizes, int n_in,
                              void* d_out, int out_size, void* d_ws, size_t ws_size,
                              hipStream_t stream) {
    const float* P = (const float*)d_in[0];   // (1, 24, 24) fp32
    const float* q = (const float*)d_in[1];   // (65536, 24, 1) fp32
    float* out     = (float*)d_out;           // (65536, 24) fp32
    (void)d_ws; (void)ws_size;

    pgd_fused<<<BATCH / BLOCKT, BLOCKT, 0, stream>>>(P, q, out);
}

// Round 5
// 366.606 us; speedup vs baseline: 2.4613x; 2.4613x over previous
//
#include <hip/hip_runtime.h>

#define NCONE 8
#define NDIM 24          // NC*3
#define PGD_ITERS 100
#define BATCH 65536
#define BLOCKT 256       // 1 elem/thread; 1024 waves = 1 wave/SIMD chip-wide
#define POW_ITERS 80
#define NPK 150          // 300 unique symmetric P entries, fp16-packed in pairs

typedef _Float16 half2v __attribute__((ext_vector_type(2)));

__device__ __forceinline__ float fast_sqrt(float x) { return __builtin_amdgcn_sqrtf(x); }
__device__ __forceinline__ float fast_rcp(float x)  { return __builtin_amdgcn_rcpf(x); }

// Upper-triangle linear index (symmetric P), i,j in any order.
constexpr int symidx(int i, int j) {
    int a = i < j ? i : j;
    int b = i < j ? j : i;
    return a * NDIM - (a * (a - 1)) / 2 + (b - a);
}
// Inverse map u -> (row, col) of the upper triangle (constant-folds under unroll).
constexpr int u2i(int u) {
    int i = 0;
    while (u >= NDIM - i) { u -= NDIM - i; ++i; }
    return i;
}
constexpr int u2j(int u) {
    int i = 0;
    while (u >= NDIM - i) { u -= NDIM - i; ++i; }
    return i + u;
}

// SOC projection of one cone (head t, tail (x0,x1)) — matches reference.
__device__ __forceinline__ void soc_proj(float& t, float& x0, float& x1) {
    float n      = fast_sqrt(fmaf(x0, x0, x1 * x1));
    float coef   = 0.5f * (t + n);
    float safe_n = (n > 0.0f) ? n : 1.0f;
    float sc     = coef * fast_rcp(safe_n);
    bool inside  = (n <= t);
    bool below   = (n <= -t);
    float tn = inside ? t    : (below ? 0.0f : coef);
    float s  = inside ? 1.0f : (below ? 0.0f : sc);
    t = tn; x0 *= s; x1 *= s;
}

// ---------------------------------------------------------------------------
// Fused kernel, v5.
//
// R1: LICM hoisted LDS-P -> 256 VGPR + scratch spill (2.7 GB), 836 us.
// R2: LDS broadcast, 1 wave/SIMD: ds_read latency exposed, 349 us.
// R3: 2 elem/thread -> half the SIMDs idle, 396 us.
// R4: SMEM-streamed P: s_load lgkmcnt stalls at 1 wave/SIMD, 878 us.
// Lesson: at 65536 threads we get exactly 1 wave/SIMD — ANY memory pipe in
// the inner loop dies on exposed latency. So: NO memory in the loop.
//
// v5: P is symmetric (300 unique floats); packed as 150 x fp16-pair VGPRs.
// Matvec = 576 x fma(f32, fpext(f16), f32) -> v_fma_mix_f32 (mad-mix
// combine), full-rate VALU, zero loads. Per-iteration asm launder of the
// packed regs ("+v", no memory clobber) stops cross-iteration hoist/CSE of
// the f16->f32 extractions (R1 failure mode). Budget: 150 P + 72 state +
// temps ~= 240 VGPR < 256 cap.
// ---------------------------------------------------------------------------
__global__ __launch_bounds__(BLOCKT, 1) void pgd_fused(const float* __restrict__ P,
                                                       const float* __restrict__ q,
                                                       float* __restrict__ out) {
    __shared__ __align__(16) float sP[NDIM * NDIM];   // staging for pow-iter + pack
    __shared__ float sQ[BLOCKT * (NDIM + 1)];         // coalescing buffer, stride 25

    const int tid  = threadIdx.x;
    const int base = blockIdx.x * (BLOCKT * NDIM);

    for (int i = tid; i < NDIM * NDIM; i += BLOCKT)
        sP[i] = P[i];
    for (int idx = tid; idx < BLOCKT * NDIM; idx += BLOCKT) {
        int r = idx / NDIM;
        int c = idx - r * NDIM;
        sQ[r * (NDIM + 1) + c] = q[base + idx];
    }
    __syncthreads();

    // --- step = 1/lambda_max(P): per-wave power iteration + Rayleigh ---
    // (zero inter-block state — R2's graph-replay divergence lesson)
    const int lane = tid & 63;
    float step;
    {
        float p[NDIM];
#pragma unroll
        for (int j = 0; j < NDIM; ++j)
            p[j] = (lane < NDIM) ? sP[lane * NDIM + j] : 0.0f;
        float v = (lane < NDIM) ? (1.0f + 0.01f * (float)lane) : 0.0f;

        for (int it = 0; it < POW_ITERS; ++it) {
            float w = 0.0f;
#pragma unroll
            for (int j = 0; j < NDIM; ++j)
                w = fmaf(p[j], __shfl(v, j, 64), w);
            float n2 = w * w;
#pragma unroll
            for (int off = 32; off >= 1; off >>= 1)
                n2 += __shfl_xor(n2, off, 64);
            v = w * rsqrtf(n2);
        }
        float w = 0.0f;
#pragma unroll
        for (int j = 0; j < NDIM; ++j)
            w = fmaf(p[j], __shfl(v, j, 64), w);
        float num = v * w;
        float den = v * v;
#pragma unroll
        for (int off = 32; off >= 1; off >>= 1) {
            num += __shfl_xor(num, off, 64);
            den += __shfl_xor(den, off, 64);
        }
        step = den / num;   // identical on every lane/wave/block
    }

    // --- pack symmetric P (upper triangle, 300 fp16) into 150 VGPRs ---
    unsigned phw[NPK];
#pragma unroll
    for (int k = 0; k < NPK; ++k) {
        float a = sP[u2i(2 * k)     * NDIM + u2j(2 * k)];
        float b = sP[u2i(2 * k + 1) * NDIM + u2j(2 * k + 1)];
        half2v hv;
        hv[0] = (_Float16)a;
        hv[1] = (_Float16)b;
        phw[k] = __builtin_bit_cast(unsigned, hv);
    }

    // --- per-thread state in VGPRs ---
    float lq[NDIM], l[NDIM];
#pragma unroll
    for (int j = 0; j < NDIM; ++j) {
        lq[j] = sQ[tid * (NDIM + 1) + j];
        l[j]  = 0.0f;
    }

#pragma clang loop unroll(disable)
    for (int it = 0; it < PGD_ITERS; ++it) {
        // Launder the packed-P registers: values are redefined each iteration
        // from the compiler's view, so the 576 f16->f32 extractions cannot be
        // hoisted/CSE'd across iterations (R1 register-blowup lesson). No
        // memory clobber — zero instructions emitted.
#pragma unroll
        for (int k = 0; k < NPK; ++k)
            asm volatile("" : "+v"(phw[k]));

        float g[NDIM];
#pragma unroll
        for (int j = 0; j < NDIM; ++j)
            g[j] = lq[j];

        // g += P l  (P symmetric, fp16-packed; fma(f32, fpext(f16), f32)
        // -> v_fma_mix_f32, zero memory traffic)
#pragma unroll
        for (int i = 0; i < NDIM; ++i) {
            float li = l[i];
#pragma unroll
            for (int j = 0; j < NDIM; ++j) {
                const int u = symidx(i, j);
                half2v hv = __builtin_bit_cast(half2v, phw[u >> 1]);
                g[j] = fmaf(li, (float)hv[u & 1], g[j]);
            }
        }

        // y = l - step*g
#pragma unroll
        for (int j = 0; j < NDIM; ++j)
            g[j] = fmaf(-step, g[j], l[j]);

        // project onto product of 8 SOCs
#pragma unroll
        for (int c = 0; c < NCONE; ++c)
            soc_proj(g[c], g[NCONE + 2 * c], g[NCONE + 2 * c + 1]);

#pragma unroll
        for (int j = 0; j < NDIM; ++j)
            l[j] = g[j];
    }

    // --- coalesced store through padded LDS ---
    __syncthreads();
#pragma unroll
    for (int j = 0; j < NDIM; ++j)
        sQ[tid * (NDIM + 1) + j] = l[j];
    __syncthreads();
    for (int idx = tid; idx < BLOCKT * NDIM; idx += BLOCKT) {
        int r = idx / NDIM;
        int c = idx - r * NDIM;
        out[base + idx] = sQ[r * (NDIM + 1) + c];
    }
}

extern "C" void kernel_launch(void* const* d_in, const int* in_sizes, int n_in,
                              void* d_out, int out_size, void* d_ws, size_t ws_size,
                              hipStream_t stream) {
    const float* P = (const float*)d_in[0];   // (1, 24, 24) fp32
    const float* q = (const float*)d_in[1];   // (65536, 24, 1) fp32
    float* out     = (float*)d_out;           // (65536, 24) fp32
    (void)d_ws; (void)ws_size;

    pgd_fused<<<BATCH / BLOCKT, BLOCKT, 0, stream>>>(P, q, out);
}

// Round 6
// 340.633 us; speedup vs baseline: 2.6489x; 1.0762x over previous
//
#include <hip/hip_runtime.h>

#define NCONE 8
#define NDIM 24          // NC*3
#define PGD_ITERS 100
#define BATCH 65536
#define BLOCKT 256       // 1 elem/thread; 1024 waves = 1 wave/SIMD chip-wide
#define POW_ITERS 80
#define NPK 150          // 300 unique symmetric P entries, fp16-packed in pairs

typedef _Float16 half2v __attribute__((ext_vector_type(2)));

__device__ __forceinline__ float fast_sqrt(float x) { return __builtin_amdgcn_sqrtf(x); }
__device__ __forceinline__ float fast_rcp(float x)  { return __builtin_amdgcn_rcpf(x); }

// Upper-triangle linear index (symmetric P), i,j in any order.
constexpr int symidx(int i, int j) {
    int a = i < j ? i : j;
    int b = i < j ? j : i;
    return a * NDIM - (a * (a - 1)) / 2 + (b - a);
}
constexpr int u2i(int u) {
    int i = 0;
    while (u >= NDIM - i) { u -= NDIM - i; ++i; }
    return i;
}
constexpr int u2j(int u) {
    int i = 0;
    while (u >= NDIM - i) { u -= NDIM - i; ++i; }
    return i + u;
}

// SOC projection of one cone (head t, tail (x0,x1)) — matches reference.
__device__ __forceinline__ void soc_proj(float& t, float& x0, float& x1) {
    float n      = fast_sqrt(fmaf(x0, x0, x1 * x1));
    float coef   = 0.5f * (t + n);
    float safe_n = (n > 0.0f) ? n : 1.0f;
    float sc     = coef * fast_rcp(safe_n);
    bool inside  = (n <= t);
    bool below   = (n <= -t);
    float tn = inside ? t    : (below ? 0.0f : coef);
    float s  = inside ? 1.0f : (below ? 0.0f : sc);
    t = tn; x0 *= s; x1 *= s;
}

// g(f32) += li(f32) * f16 half of pk — ONE full-rate VALU op, no extraction.
// op_sel_hi[1]=1 marks src1 as f16; op_sel[1] picks the half.
#define FMA_MIX_LO(g_, li_, pk_)                                               \
    asm("v_fma_mix_f32 %0, %1, %2, %0 op_sel:[0,0,0] op_sel_hi:[0,1,0]"        \
        : "+v"(g_) : "v"(li_), "v"(pk_))
#define FMA_MIX_HI(g_, li_, pk_)                                               \
    asm("v_fma_mix_f32 %0, %1, %2, %0 op_sel:[0,1,0] op_sel_hi:[0,1,0]"        \
        : "+v"(g_) : "v"(li_), "v"(pk_))

// ---------------------------------------------------------------------------
// Fused kernel, v6.
//
// R1: LICM hoist of LDS-P -> 256 VGPR + 2.7 GB scratch, 836 us.
// R2: LDS broadcast @1 wave/SIMD: ds_read latency exposed, 349 us.
// R3: 2 elem/thread -> half the SIMDs idle, 396 us.
// R4: SMEM-streamed P: s_load stalls @1 wave/SIMD, 878 us.
// R5: f16-packed P in regs: right idea, wrong codegen — VGPR_Count=156
//     proves the allocator parked phw in AGPRs (accvgpr shuttle) and the
//     f16 path was extract+cvt+fma: ~2150 insts/iter, VALUBusy 53%, 338 us.
//
// v6: emit the 576 matvec FMAs as inline-asm v_fma_mix_f32 (f32 += f32*f16,
// one full-rate op, op_sel picks the packed half). The "v" operands pin phw
// into arch VGPRs; g[j] is read-modify-write per statement so nothing is
// loop-hoistable (no launder needed). ~1600 VALU cyc/iter -> ~67 us loop.
// ---------------------------------------------------------------------------
__global__ __launch_bounds__(BLOCKT, 1) void pgd_fused(const float* __restrict__ P,
                                                       const float* __restrict__ q,
                                                       float* __restrict__ out) {
    __shared__ __align__(16) float sP[NDIM * NDIM];   // staging: pow-iter + pack
    __shared__ float sQ[BLOCKT * (NDIM + 1)];         // coalescing buffer, stride 25

    const int tid  = threadIdx.x;
    const int base = blockIdx.x * (BLOCKT * NDIM);

    for (int i = tid; i < NDIM * NDIM; i += BLOCKT)
        sP[i] = P[i];
    for (int idx = tid; idx < BLOCKT * NDIM; idx += BLOCKT) {
        int r = idx / NDIM;
        int c = idx - r * NDIM;
        sQ[r * (NDIM + 1) + c] = q[base + idx];
    }
    __syncthreads();

    // --- step = 1/lambda_max(P): per-wave power iteration + Rayleigh ---
    // (zero inter-block state — R2's graph-replay divergence lesson)
    const int lane = tid & 63;
    float step;
    {
        float p[NDIM];
#pragma unroll
        for (int j = 0; j < NDIM; ++j)
            p[j] = (lane < NDIM) ? sP[lane * NDIM + j] : 0.0f;
        float v = (lane < NDIM) ? (1.0f + 0.01f * (float)lane) : 0.0f;

        for (int it = 0; it < POW_ITERS; ++it) {
            float w = 0.0f;
#pragma unroll
            for (int j = 0; j < NDIM; ++j)
                w = fmaf(p[j], __shfl(v, j, 64), w);
            float n2 = w * w;
#pragma unroll
            for (int off = 32; off >= 1; off >>= 1)
                n2 += __shfl_xor(n2, off, 64);
            v = w * rsqrtf(n2);
        }
        float w = 0.0f;
#pragma unroll
        for (int j = 0; j < NDIM; ++j)
            w = fmaf(p[j], __shfl(v, j, 64), w);
        float num = v * w;
        float den = v * v;
#pragma unroll
        for (int off = 32; off >= 1; off >>= 1) {
            num += __shfl_xor(num, off, 64);
            den += __shfl_xor(den, off, 64);
        }
        step = den / num;   // identical on every lane/wave/block
    }

    // --- pack symmetric P (upper triangle, 300 fp16) into 150 VGPRs ---
    unsigned phw[NPK];
#pragma unroll
    for (int k = 0; k < NPK; ++k) {
        float a = sP[u2i(2 * k)     * NDIM + u2j(2 * k)];
        float b = sP[u2i(2 * k + 1) * NDIM + u2j(2 * k + 1)];
        half2v hv;
        hv[0] = (_Float16)a;
        hv[1] = (_Float16)b;
        phw[k] = __builtin_bit_cast(unsigned, hv);
    }

    // --- per-thread state in VGPRs ---
    float lq[NDIM], l[NDIM];
#pragma unroll
    for (int j = 0; j < NDIM; ++j) {
        lq[j] = sQ[tid * (NDIM + 1) + j];
        l[j]  = 0.0f;
    }

#pragma clang loop unroll(disable)
    for (int it = 0; it < PGD_ITERS; ++it) {
        float g[NDIM];
#pragma unroll
        for (int j = 0; j < NDIM; ++j)
            g[j] = lq[j];

        // g += P l — 576 v_fma_mix_f32, zero memory traffic, zero extracts.
#pragma unroll
        for (int i = 0; i < NDIM; ++i) {
            float li = l[i];
#pragma unroll
            for (int j = 0; j < NDIM; ++j) {
                const int u = symidx(i, j);   // compile-time under full unroll
                if ((u & 1) == 0) {
                    FMA_MIX_LO(g[j], li, phw[u >> 1]);
                } else {
                    FMA_MIX_HI(g[j], li, phw[u >> 1]);
                }
            }
        }

        // y = l - step*g
#pragma unroll
        for (int j = 0; j < NDIM; ++j)
            g[j] = fmaf(-step, g[j], l[j]);

        // project onto product of 8 SOCs
#pragma unroll
        for (int c = 0; c < NCONE; ++c)
            soc_proj(g[c], g[NCONE + 2 * c], g[NCONE + 2 * c + 1]);

#pragma unroll
        for (int j = 0; j < NDIM; ++j)
            l[j] = g[j];
    }

    // --- coalesced store through padded LDS ---
    __syncthreads();
#pragma unroll
    for (int j = 0; j < NDIM; ++j)
        sQ[tid * (NDIM + 1) + j] = l[j];
    __syncthreads();
    for (int idx = tid; idx < BLOCKT * NDIM; idx += BLOCKT) {
        int r = idx / NDIM;
        int c = idx - r * NDIM;
        out[base + idx] = sQ[r * (NDIM + 1) + c];
    }
}

extern "C" void kernel_launch(void* const* d_in, const int* in_sizes, int n_in,
                              void* d_out, int out_size, void* d_ws, size_t ws_size,
                              hipStream_t stream) {
    const float* P = (const float*)d_in[0];   // (1, 24, 24) fp32
    const float* q = (const float*)d_in[1];   // (65536, 24, 1) fp32
    float* out     = (float*)d_out;           // (65536, 24) fp32
    (void)d_ws; (void)ws_size;

    pgd_fused<<<BATCH / BLOCKT, BLOCKT, 0, stream>>>(P, q, out);
}